// Round 3
// baseline (97.825 us; speedup 1.0000x reference)
//
#include <hip/hip_runtime.h>
#include <hip/hip_fp16.h>

// Problem constants (from the reference).
constexpr int S  = 51;   // seq positions
constexpr int V  = 64;   // vocab
constexpr int E  = 4;    // embedding dim
constexpr int H1 = 5;
constexpr int H2 = 7;
constexpr int D  = 64;   // output dim

// ---------------------------------------------------------------------------
// Kernel 1: build fp16 table Y[s][v][d] = tanh(W3[s] @ h2(s,v) + b3[s]).
// Whole MLP depends only on (s, token): 3264 rows x 64 d, 408 KB fp16.
// ---------------------------------------------------------------------------
__global__ void build_table_kernel(const float* __restrict__ emb,
                                   const float* __restrict__ W1,
                                   const float* __restrict__ b1,
                                   const float* __restrict__ W2,
                                   const float* __restrict__ b2,
                                   const float* __restrict__ W3,
                                   const float* __restrict__ b3,
                                   __half* __restrict__ Y) {
  const int sv = blockIdx.x;     // sv = s*64 + v
  const int s  = sv >> 6;
  const int d  = threadIdx.x;    // 0..63

  float e[E];
#pragma unroll
  for (int i = 0; i < E; ++i) e[i] = emb[sv * E + i];

  float h1[H1];
#pragma unroll
  for (int h = 0; h < H1; ++h) {
    float a = b1[s * H1 + h];
#pragma unroll
    for (int i = 0; i < E; ++i) a = fmaf(W1[(s * H1 + h) * E + i], e[i], a);
    h1[h] = (a >= 0.f) ? a : 0.01f * a;   // leaky_relu
  }

  float h2[H2];
#pragma unroll
  for (int g = 0; g < H2; ++g) {
    float a = b2[s * H2 + g];
#pragma unroll
    for (int h = 0; h < H1; ++h) a = fmaf(W2[(s * H2 + g) * H1 + h], h1[h], a);
    h2[g] = (a >= 0.f) ? a : 0.01f * a;
  }

  float a = b3[s * D + d];
#pragma unroll
  for (int g = 0; g < H2; ++g) a = fmaf(W3[(s * D + d) * H2 + g], h2[g], a);

  Y[sv * D + d] = __float2half(tanhf(a));
}

// ---------------------------------------------------------------------------
// Kernel 2: out[b][d] = sum_s Y[s, x[b,s], d]
// Wave = 8 batch rows; lane = (rg = row-in-octet) * 8 + (li = d-octet).
// Tokens pre-gathered with s*64 FOLDED IN (tok -> direct table-row index),
// so the per-s address is one v_lshl_or against a loop-invariant base.
// Inner accumulation in packed fp16 (v_pk_add_f16), promoted to fp32 every
// 4 s (error <= ~0.02 worst case, under the 0.0625 existing floor).
// ---------------------------------------------------------------------------
__global__ __launch_bounds__(256) void gather_sum_kernel(
    const int* __restrict__ x, const __half* __restrict__ Y,
    float* __restrict__ out, int B) {
  const int lane  = threadIdx.x & 63;
  const int li    = lane & 7;                         // d-octet index
  const int wid   = threadIdx.x >> 6;                 // wave id 0..3
  const int row   = (blockIdx.x * 4 + wid) * 8 + (lane >> 3);

  // Pre-gather row indices: tok[j] = x[row, s] + s*64  for s = j*8 + li.
  int tok[7];
#pragma unroll
  for (int j = 0; j < 7; ++j) {
    const int s = j * 8 + li;
    tok[j] = (s < S) ? (x[row * S + s] + (s << 6)) : 0;
  }

  const int rgsel = lane & 56;                        // rg<<3
  const int li16  = li << 4;                          // byte offset of d-octet
  const char* Yb  = (const char*)Y;

  float acc[8];
#pragma unroll
  for (int k = 0; k < 8; ++k) acc[k] = 0.f;

  // 13 chunks of 4 s (last chunk has 3).
#pragma unroll
  for (int c = 0; c < 13; ++c) {
    __half2 a16[4];
#pragma unroll
    for (int k = 0; k < 4; ++k) a16[k] = __half2(__float2half(0.f), __float2half(0.f));

#pragma unroll
    for (int j = 0; j < 4; ++j) {
      const int s = c * 4 + j;
      if (s < S) {
        // Table-row index for (this lane's row, s): lane rg*8+(s&7), slot s>>3.
        const int r = __shfl(tok[s >> 3], rgsel | (s & 7), 64);
        const uint4 v = *reinterpret_cast<const uint4*>(Yb + ((r << 7) | li16));
        union { uint4 u; __half2 h[4]; } cv; cv.u = v;
#pragma unroll
        for (int k = 0; k < 4; ++k) a16[k] = __hadd2(a16[k], cv.h[k]);
      }
    }

#pragma unroll
    for (int k = 0; k < 4; ++k) {
      const float2 f = __half22float2(a16[k]);
      acc[2 * k]     += f.x;
      acc[2 * k + 1] += f.y;
    }
  }

  // Wave writes 2 KB contiguous (8 consecutive rows x 256 B).
  float4* o = reinterpret_cast<float4*>(out + row * D + (li << 3));
  o[0] = make_float4(acc[0], acc[1], acc[2], acc[3]);
  o[1] = make_float4(acc[4], acc[5], acc[6], acc[7]);
}

// ---------------------------------------------------------------------------
extern "C" void kernel_launch(void* const* d_in, const int* in_sizes, int n_in,
                              void* d_out, int out_size, void* d_ws, size_t ws_size,
                              hipStream_t stream) {
  const int*   x   = (const int*)d_in[0];
  const float* emb = (const float*)d_in[1];
  const float* W1  = (const float*)d_in[2];
  const float* b1  = (const float*)d_in[3];
  const float* W2  = (const float*)d_in[4];
  const float* b2  = (const float*)d_in[5];
  const float* W3  = (const float*)d_in[6];
  const float* b3  = (const float*)d_in[7];

  const int B = in_sizes[0] / S;          // 65536
  __half* Y = (__half*)d_ws;              // S*V*D halves = 417,792 bytes

  build_table_kernel<<<S * V, D, 0, stream>>>(emb, W1, b1, W2, b2, W3, b3, Y);

  // 32 batch rows per 256-thread block (8 per wave).
  gather_sum_kernel<<<B / 32, 256, 0, stream>>>(x, Y, (float*)d_out, B);
}